// Round 1
// baseline (227.384 us; speedup 1.0000x reference)
//
#include <hip/hip_runtime.h>
#include <hip/hip_bf16.h>

// SlotAttention fused pipeline for MI355X (gfx950).
// B=64, NS=11, NK=4096, all feature dims = 128, NUM_ITER=2.
//
// Per iteration:
//   kq: q = LN(query) @ Wq * scale            (tiny)
//   ks: stream over keys: LN(x) -> k,v proj (MFMA) -> logits (MFMA) ->
//       softmax over 11 slots (wave-local) -> p@v accumulate (MFMA)
//       partials atomically added to upd_acc / d_acc
//   ku: upd = upd_acc/(d_acc+eps); GRU cell -> next query

#define NKEYS 4096

typedef short short8 __attribute__((ext_vector_type(8)));
typedef float f32x4 __attribute__((ext_vector_type(4)));

__device__ __forceinline__ unsigned short f2bf(float x) {
    unsigned u = __float_as_uint(x);
    u += 0x7fffu + ((u >> 16) & 1u);   // round-to-nearest-even
    return (unsigned short)(u >> 16);
}

// ---------------- kernel Q: q = LN(query) @ Wq * scale ----------------
__global__ void kq(const float* __restrict__ query, const float* __restrict__ g,
                   const float* __restrict__ be, const float* __restrict__ Wq,
                   float* __restrict__ qout) {
    int bm = blockIdx.x;        // b*11 + m
    int c = threadIdx.x;        // 0..127
    __shared__ float xs[128];
    __shared__ float red[4];
    float x = query[bm * 128 + c];
    float s = x, ss = x * x;
#pragma unroll
    for (int mask = 1; mask < 64; mask <<= 1) {
        s += __shfl_xor(s, mask);
        ss += __shfl_xor(ss, mask);
    }
    int wid = threadIdx.x >> 6;
    if ((threadIdx.x & 63) == 0) { red[wid] = s; red[2 + wid] = ss; }
    __syncthreads();
    s = red[0] + red[1]; ss = red[2] + red[3];
    float mean = s * (1.f / 128.f);
    float var = ss * (1.f / 128.f) - mean * mean;
    float rstd = rsqrtf(var + 1e-5f);
    xs[c] = (x - mean) * rstd * g[c] + be[c];
    __syncthreads();
    float acc = 0.f;
#pragma unroll 8
    for (int k = 0; k < 128; k++) acc += xs[k] * Wq[k * 128 + c];
    qout[bm * 128 + c] = acc * 0.088388347648318447f;   // 1/sqrt(128)
}

// ---------------- kernel S: streaming attention over keys ----------------
__global__ __launch_bounds__(256) void ks(
    const float* __restrict__ inputs, const float* __restrict__ gkv,
    const float* __restrict__ bkv, const float* __restrict__ Wk,
    const float* __restrict__ Wv, const float* __restrict__ qbuf,
    float* __restrict__ upd_acc, float* __restrict__ d_acc) {
    // LDS: x_tile [64][128] bf16 (swz), k_tile [64][128] bf16 (swz),
    //      vT [128][64] bf16 (swz), p [16][64] bf16 (swz)
    __shared__ __align__(16) char smem[51200];
    const int XO = 0, KO = 16384, VB = 32768, PO = 49152;

    int tid = threadIdx.x;
    int b = blockIdx.x >> 4, g = blockIdx.x & 15;
    int w = tid >> 6, lane = tid & 63, hi = lane >> 4, lo = lane & 15;

    // --- preload Wk/Wv B-fragments (wave w owns output cols [32w,32w+32)) ---
    short8 bk[2][4], bv[2][4];
#pragma unroll
    for (int ct = 0; ct < 2; ct++) {
        int col = w * 32 + ct * 16 + lo;
#pragma unroll
        for (int kc = 0; kc < 4; kc++) {
            short8 fk, fv;
#pragma unroll
            for (int j = 0; j < 8; j++) {
                int rr = kc * 32 + hi * 8 + j;
                fk[j] = (short)f2bf(Wk[rr * 128 + col]);
                fv[j] = (short)f2bf(Wv[rr * 128 + col]);
            }
            bk[ct][kc] = fk; bv[ct][kc] = fv;
        }
    }
    // --- preload q A-fragments (rows 11..15 zero) ---
    short8 qa[4];
    {
        int m = lo;
#pragma unroll
        for (int kc = 0; kc < 4; kc++) {
            short8 f;
#pragma unroll
            for (int j = 0; j < 8; j++)
                f[j] = (m < 11) ? (short)f2bf(qbuf[(b * 11 + m) * 128 + kc * 32 + hi * 8 + j])
                                : (short)0;
            qa[kc] = f;
        }
    }
    int col4 = tid & 31;
    float4 g4  = *(const float4*)(gkv + col4 * 4);
    float4 be4 = *(const float4*)(bkv + col4 * 4);

    f32x4 uacc0 = {0, 0, 0, 0}, uacc1 = {0, 0, 0, 0};
    float dacc[4] = {0, 0, 0, 0};

    const float4* inp4 = (const float4*)(inputs + ((size_t)b * NKEYS + g * 256) * 128);
    int a_ = tid >> 5;   // row-group within tile

    for (int t = 0; t < 4; t++) {
        // ---- LN: registers + 32-lane shfl reduce -> bf16 x_tile ----
#pragma unroll
        for (int i = 0; i < 8; i++) {
            int f = tid + 256 * i;                 // float4 idx within 64x32 tile
            float4 xv = inp4[t * 2048 + f];
            int row = a_ + 8 * i;
            float s = xv.x + xv.y + xv.z + xv.w;
            float ss = xv.x * xv.x + xv.y * xv.y + xv.z * xv.z + xv.w * xv.w;
#pragma unroll
            for (int mask = 1; mask < 32; mask <<= 1) {
                s += __shfl_xor(s, mask);
                ss += __shfl_xor(ss, mask);
            }
            float mean = s * (1.f / 128.f);
            float var = ss * (1.f / 128.f) - mean * mean;
            float rstd = rsqrtf(var + 1e-5f);
            unsigned short h0 = f2bf((xv.x - mean) * rstd * g4.x + be4.x);
            unsigned short h1 = f2bf((xv.y - mean) * rstd * g4.y + be4.y);
            unsigned short h2 = f2bf((xv.z - mean) * rstd * g4.z + be4.z);
            unsigned short h3 = f2bf((xv.w - mean) * rstd * g4.w + be4.w);
            uint2 pk;
            pk.x = (unsigned)h0 | ((unsigned)h1 << 16);
            pk.y = (unsigned)h2 | ((unsigned)h3 << 16);
            int byte = row * 256 + ((col4 * 8) ^ ((row & 7) << 4));
            *(uint2*)(smem + XO + byte) = pk;
        }
        __syncthreads();

        // ---- projections: k_tile = x@Wk, vT = (x@Wv)^T ----
#pragma unroll
        for (int mt = 0; mt < 4; mt++) {
            f32x4 ka0 = {0,0,0,0}, ka1 = {0,0,0,0}, va0 = {0,0,0,0}, va1 = {0,0,0,0};
            int arow = mt * 16 + lo;
#pragma unroll
            for (int kc = 0; kc < 4; kc++) {
                int abyte = arow * 256 + ((kc * 64 + hi * 16) ^ ((arow & 7) << 4));
                short8 af = *(short8*)(smem + XO + abyte);
                ka0 = __builtin_amdgcn_mfma_f32_16x16x32_bf16(af, bk[0][kc], ka0, 0, 0, 0);
                ka1 = __builtin_amdgcn_mfma_f32_16x16x32_bf16(af, bk[1][kc], ka1, 0, 0, 0);
                va0 = __builtin_amdgcn_mfma_f32_16x16x32_bf16(af, bv[0][kc], va0, 0, 0, 0);
                va1 = __builtin_amdgcn_mfma_f32_16x16x32_bf16(af, bv[1][kc], va1, 0, 0, 0);
            }
#pragma unroll
            for (int r = 0; r < 4; r++) {
                int n = mt * 16 + hi * 4 + r;
                int c0 = w * 32 + lo;
                int c1 = c0 + 16;
                *(unsigned short*)(smem + KO + n * 256 + ((c0 * 2) ^ ((n & 7) << 4))) = f2bf(ka0[r]);
                *(unsigned short*)(smem + KO + n * 256 + ((c1 * 2) ^ ((n & 7) << 4))) = f2bf(ka1[r]);
                *(unsigned short*)(smem + VB + c0 * 128 + ((n * 2) ^ ((c0 & 7) << 4))) = f2bf(va0[r]);
                *(unsigned short*)(smem + VB + c1 * 128 + ((n * 2) ^ ((c1 & 7) << 4))) = f2bf(va1[r]);
            }
        }
        __syncthreads();

        // ---- logits (wave w: keys [16w,16w+16)) + softmax over slots ----
        {
            f32x4 lacc = {0, 0, 0, 0};
            int n = w * 16 + lo;
#pragma unroll
            for (int kc = 0; kc < 4; kc++) {
                int kbyte = n * 256 + ((kc * 64 + hi * 16) ^ ((n & 7) << 4));
                short8 kf = *(short8*)(smem + KO + kbyte);
                lacc = __builtin_amdgcn_mfma_f32_16x16x32_bf16(qa[kc], kf, lacc, 0, 0, 0);
            }
            float mx = -1e30f;
#pragma unroll
            for (int r = 0; r < 4; r++) {
                int m = hi * 4 + r;
                float v = (m < 11) ? lacc[r] : -1e30f;
                mx = fmaxf(mx, v);
            }
            mx = fmaxf(mx, __shfl_xor(mx, 16));
            mx = fmaxf(mx, __shfl_xor(mx, 32));
            float p[4]; float s = 0.f;
#pragma unroll
            for (int r = 0; r < 4; r++) {
                int m = hi * 4 + r;
                p[r] = (m < 11) ? __expf(lacc[r] - mx) : 0.f;
                s += p[r];
            }
            s += __shfl_xor(s, 16);
            s += __shfl_xor(s, 32);
            float inv = 1.f / s;   // s >= 1 (max term included)
#pragma unroll
            for (int r = 0; r < 4; r++) {
                p[r] *= inv;
                dacc[r] += p[r];
                int m = hi * 4 + r;
                *(unsigned short*)(smem + PO + m * 128 + (((w * 16 + lo) * 2) ^ ((m & 7) << 4))) =
                    f2bf(p[r]);
            }
        }
        __syncthreads();

        // ---- PV: uacc += p @ v  (wave w owns v-cols [32w,32w+32)) ----
#pragma unroll
        for (int kc2 = 0; kc2 < 2; kc2++) {
            int pbyte = lo * 128 + ((kc2 * 64 + hi * 16) ^ ((lo & 7) << 4));
            short8 pf = *(short8*)(smem + PO + pbyte);
            int c0 = w * 32 + lo;
            int vb0 = c0 * 128 + ((kc2 * 64 + hi * 16) ^ ((c0 & 7) << 4));
            short8 vf0 = *(short8*)(smem + VB + vb0);
            uacc0 = __builtin_amdgcn_mfma_f32_16x16x32_bf16(pf, vf0, uacc0, 0, 0, 0);
            int c1 = c0 + 16;
            int vb1 = c1 * 128 + ((kc2 * 64 + hi * 16) ^ ((c1 & 7) << 4));
            short8 vf1 = *(short8*)(smem + VB + vb1);
            uacc1 = __builtin_amdgcn_mfma_f32_16x16x32_bf16(pf, vf1, uacc1, 0, 0, 0);
        }
        // next-iter LN only writes x_tile; barrier after LN protects k/v/p buffers
    }

    // ---- flush partials ----
#pragma unroll
    for (int r = 0; r < 4; r++) {
        int m = hi * 4 + r;
        if (m < 11) {
            atomicAdd(&upd_acc[(b * 16 + m) * 128 + w * 32 + lo], uacc0[r]);
            atomicAdd(&upd_acc[(b * 16 + m) * 128 + w * 32 + 16 + lo], uacc1[r]);
        }
    }
#pragma unroll
    for (int mask = 1; mask < 16; mask <<= 1) {
#pragma unroll
        for (int r = 0; r < 4; r++) dacc[r] += __shfl_xor(dacc[r], mask);
    }
    if (lo == 0) {
#pragma unroll
        for (int r = 0; r < 4; r++) {
            int m = hi * 4 + r;
            if (m < 11) atomicAdd(&d_acc[b * 16 + m], dacc[r]);
        }
    }
}

// ---------------- kernel U: finalize + GRU cell ----------------
__global__ void ku(const float* __restrict__ upd_acc, const float* __restrict__ d_acc,
                   const float* __restrict__ qcur,
                   const float* __restrict__ W_ir, const float* __restrict__ b_ir,
                   const float* __restrict__ W_iz, const float* __restrict__ b_iz,
                   const float* __restrict__ W_hr, const float* __restrict__ W_hz,
                   const float* __restrict__ W_in, const float* __restrict__ b_in,
                   const float* __restrict__ W_hn, const float* __restrict__ b_hn,
                   float* __restrict__ qnext) {
    int bm = blockIdx.x;
    int b = bm / 11, m = bm % 11;
    int c = threadIdx.x;
    __shared__ float us[128], qs[128];
    float den = d_acc[b * 16 + m] + 1e-8f;
    us[c] = upd_acc[(b * 16 + m) * 128 + c] / den;
    qs[c] = qcur[bm * 128 + c];
    __syncthreads();
    float air = 0, aiz = 0, ain = 0, ahr = 0, ahz = 0, ahn = 0;
#pragma unroll 4
    for (int k = 0; k < 128; k++) {
        float u = us[k], q = qs[k];
        air += u * W_ir[k * 128 + c];
        aiz += u * W_iz[k * 128 + c];
        ain += u * W_in[k * 128 + c];
        ahr += q * W_hr[k * 128 + c];
        ahz += q * W_hz[k * 128 + c];
        ahn += q * W_hn[k * 128 + c];
    }
    float r = 1.f / (1.f + expf(-(air + b_ir[c] + ahr)));
    float z = 1.f / (1.f + expf(-(aiz + b_iz[c] + ahz)));
    float n = tanhf(ain + b_in[c] + r * (ahn + b_hn[c]));
    qnext[bm * 128 + c] = (1.f - z) * n + z * qs[c];
}

// ---------------- launch ----------------
extern "C" void kernel_launch(void* const* d_in, const int* in_sizes, int n_in,
                              void* d_out, int out_size, void* d_ws, size_t ws_size,
                              hipStream_t stream) {
    const float* query   = (const float*)d_in[0];
    const float* inputs  = (const float*)d_in[1];
    const float* ln_q_g  = (const float*)d_in[2];
    const float* ln_q_b  = (const float*)d_in[3];
    const float* ln_kv_g = (const float*)d_in[4];
    const float* ln_kv_b = (const float*)d_in[5];
    const float* Wq      = (const float*)d_in[6];
    const float* Wk      = (const float*)d_in[7];
    const float* Wv      = (const float*)d_in[8];
    const float* W_ir    = (const float*)d_in[9];
    const float* b_ir    = (const float*)d_in[10];
    const float* W_iz    = (const float*)d_in[11];
    const float* b_iz    = (const float*)d_in[12];
    const float* W_hr    = (const float*)d_in[13];
    const float* W_hz    = (const float*)d_in[14];
    const float* W_in    = (const float*)d_in[15];
    const float* b_in    = (const float*)d_in[16];
    const float* W_hn    = (const float*)d_in[17];
    const float* b_hn    = (const float*)d_in[18];

    char* ws = (char*)d_ws;
    float* q_buf     = (float*)(ws);             // 64*11*128 f32
    float* query_buf = (float*)(ws + 360448);    // 64*11*128 f32
    float* upd_acc   = (float*)(ws + 720896);    // 64*16*128 f32
    float* d_acc     = (float*)(ws + 1245184);   // 64*16 f32

    const float* cur = query;
    for (int it = 0; it < 2; it++) {
        kq<<<704, 128, 0, stream>>>(cur, ln_q_g, ln_q_b, Wq, q_buf);
        hipMemsetAsync(ws + 720896, 0, 524288 + 4096, stream);
        ks<<<1024, 256, 0, stream>>>(inputs, ln_kv_g, ln_kv_b, Wk, Wv, q_buf, upd_acc, d_acc);
        float* qn = (it == 0) ? query_buf : (float*)d_out;
        ku<<<704, 128, 0, stream>>>(upd_acc, d_acc, cur,
                                    W_ir, b_ir, W_iz, b_iz, W_hr, W_hz,
                                    W_in, b_in, W_hn, b_hn, qn);
        cur = query_buf;
    }
}

// Round 2
// 197.174 us; speedup vs baseline: 1.1532x; 1.1532x over previous
//
#include <hip/hip_runtime.h>
#include <hip/hip_bf16.h>

// SlotAttention fused pipeline for MI355X (gfx950).
// B=64, NS=11, NK=4096, all feature dims = 128, NUM_ITER=2.
//
// Big-ws path:
//   ka (once): LN(inputs) -> k = x@Wk, vT = (x@Wv)^T, stored bf16 pre-swizzled
//   per iter: kq (q proj), kb (logits/softmax/PV streaming from k/v), ku (GRU)
// Fallback (small ws): original fused ks per iteration.

#define NKEYS 4096

typedef short short8 __attribute__((ext_vector_type(8)));
typedef float f32x4 __attribute__((ext_vector_type(4)));
typedef unsigned short u16x4 __attribute__((ext_vector_type(4)));

__device__ __forceinline__ unsigned short f2bf(float x) {
    unsigned u = __float_as_uint(x);
    u += 0x7fffu + ((u >> 16) & 1u);   // round-to-nearest-even
    return (unsigned short)(u >> 16);
}

__device__ __forceinline__ void gll16(const void* g, void* l) {
    __builtin_amdgcn_global_load_lds(
        (const __attribute__((address_space(1))) unsigned int*)g,
        (__attribute__((address_space(3))) unsigned int*)l, 16, 0, 0);
}

// ---------------- kernel Q: q = LN(query) @ Wq * scale ----------------
__global__ void kq(const float* __restrict__ query, const float* __restrict__ g,
                   const float* __restrict__ be, const float* __restrict__ Wq,
                   float* __restrict__ qout) {
    int bm = blockIdx.x;        // b*11 + m
    int c = threadIdx.x;        // 0..127
    __shared__ float xs[128];
    __shared__ float red[4];
    float x = query[bm * 128 + c];
    float s = x, ss = x * x;
#pragma unroll
    for (int mask = 1; mask < 64; mask <<= 1) {
        s += __shfl_xor(s, mask);
        ss += __shfl_xor(ss, mask);
    }
    int wid = threadIdx.x >> 6;
    if ((threadIdx.x & 63) == 0) { red[wid] = s; red[2 + wid] = ss; }
    __syncthreads();
    s = red[0] + red[1]; ss = red[2] + red[3];
    float mean = s * (1.f / 128.f);
    float var = ss * (1.f / 128.f) - mean * mean;
    float rstd = rsqrtf(var + 1e-5f);
    xs[c] = (x - mean) * rstd * g[c] + be[c];
    __syncthreads();
    float acc = 0.f;
#pragma unroll 8
    for (int k = 0; k < 128; k++) acc += xs[k] * Wq[k * 128 + c];
    qout[bm * 128 + c] = acc * 0.088388347648318447f;   // 1/sqrt(128)
}

// ---------------- kernel A: LN + k/v projection, materialize (once) ----------------
// kg tile layout (per 64-key tile, 16 KB): byte = n*256 + ((c*2) ^ ((n&7)<<4))
// vg tile layout (vT, 16 KB):             byte = c*128 + ((n*2) ^ ((c&7)<<4))
__global__ __launch_bounds__(256) void ka(
    const float* __restrict__ inputs, const float* __restrict__ gkv,
    const float* __restrict__ bkv, const float* __restrict__ Wk,
    const float* __restrict__ Wv, char* __restrict__ kg, char* __restrict__ vg) {
    __shared__ __align__(16) char smem[49152];   // XO 16K, KO 16K, VB 16K
    const int XO = 0, KO = 16384, VB = 32768;

    int tid = threadIdx.x;
    int b = blockIdx.x >> 5, g2 = blockIdx.x & 31;   // 2 tiles per block
    int w = tid >> 6, lane = tid & 63, hi = lane >> 4, lo = lane & 15;

    short8 bk[2][4], bv[2][4];
#pragma unroll
    for (int ct = 0; ct < 2; ct++) {
        int col = w * 32 + ct * 16 + lo;
#pragma unroll
        for (int kc = 0; kc < 4; kc++) {
            short8 fk, fv;
#pragma unroll
            for (int j = 0; j < 8; j++) {
                int rr = kc * 32 + hi * 8 + j;
                fk[j] = (short)f2bf(Wk[rr * 128 + col]);
                fv[j] = (short)f2bf(Wv[rr * 128 + col]);
            }
            bk[ct][kc] = fk; bv[ct][kc] = fv;
        }
    }
    int col4 = tid & 31;
    float4 g4  = *(const float4*)(gkv + col4 * 4);
    float4 be4 = *(const float4*)(bkv + col4 * 4);

    const float4* inp4 = (const float4*)(inputs + ((size_t)b * NKEYS + g2 * 128) * 128);
    int a_ = tid >> 5;

    float4 xa[8];
#pragma unroll
    for (int i = 0; i < 8; i++) xa[i] = inp4[tid + 256 * i];

#pragma unroll
    for (int t = 0; t < 2; t++) {
        float4 xb[8];
        if (t == 0) {
#pragma unroll
            for (int i = 0; i < 8; i++) xb[i] = inp4[2048 + tid + 256 * i];
        }
        // ---- LN -> bf16 x_tile ----
#pragma unroll
        for (int i = 0; i < 8; i++) {
            float4 xv = xa[i];
            int row = a_ + 8 * i;
            float s = xv.x + xv.y + xv.z + xv.w;
            float ss = xv.x * xv.x + xv.y * xv.y + xv.z * xv.z + xv.w * xv.w;
#pragma unroll
            for (int mask = 1; mask < 32; mask <<= 1) {
                s += __shfl_xor(s, mask);
                ss += __shfl_xor(ss, mask);
            }
            float mean = s * (1.f / 128.f);
            float var = ss * (1.f / 128.f) - mean * mean;
            float rstd = rsqrtf(var + 1e-5f);
            unsigned short h0 = f2bf((xv.x - mean) * rstd * g4.x + be4.x);
            unsigned short h1 = f2bf((xv.y - mean) * rstd * g4.y + be4.y);
            unsigned short h2 = f2bf((xv.z - mean) * rstd * g4.z + be4.z);
            unsigned short h3 = f2bf((xv.w - mean) * rstd * g4.w + be4.w);
            uint2 pk;
            pk.x = (unsigned)h0 | ((unsigned)h1 << 16);
            pk.y = (unsigned)h2 | ((unsigned)h3 << 16);
            int byte = row * 256 + ((col4 * 8) ^ ((row & 7) << 4));
            *(uint2*)(smem + XO + byte) = pk;
        }
        __syncthreads();

        // ---- projections ----
#pragma unroll
        for (int mt = 0; mt < 4; mt++) {
            f32x4 ka0 = {0,0,0,0}, ka1 = {0,0,0,0}, va0 = {0,0,0,0}, va1 = {0,0,0,0};
            int arow = mt * 16 + lo;
#pragma unroll
            for (int kc = 0; kc < 4; kc++) {
                int abyte = arow * 256 + ((kc * 64 + hi * 16) ^ ((arow & 7) << 4));
                short8 af = *(short8*)(smem + XO + abyte);
                ka0 = __builtin_amdgcn_mfma_f32_16x16x32_bf16(af, bk[0][kc], ka0, 0, 0, 0);
                ka1 = __builtin_amdgcn_mfma_f32_16x16x32_bf16(af, bk[1][kc], ka1, 0, 0, 0);
                va0 = __builtin_amdgcn_mfma_f32_16x16x32_bf16(af, bv[0][kc], va0, 0, 0, 0);
                va1 = __builtin_amdgcn_mfma_f32_16x16x32_bf16(af, bv[1][kc], va1, 0, 0, 0);
            }
            int c0 = w * 32 + lo, c1 = c0 + 16;
            int n0 = mt * 16 + hi * 4;
#pragma unroll
            for (int r = 0; r < 4; r++) {
                int n = n0 + r;
                *(unsigned short*)(smem + KO + n * 256 + ((c0 * 2) ^ ((n & 7) << 4))) = f2bf(ka0[r]);
                *(unsigned short*)(smem + KO + n * 256 + ((c1 * 2) ^ ((n & 7) << 4))) = f2bf(ka1[r]);
            }
            u16x4 pv0, pv1;
#pragma unroll
            for (int r = 0; r < 4; r++) { pv0[r] = f2bf(va0[r]); pv1[r] = f2bf(va1[r]); }
            *(u16x4*)(smem + VB + c0 * 128 + ((n0 * 2) ^ ((c0 & 7) << 4))) = pv0;
            *(u16x4*)(smem + VB + c1 * 128 + ((n0 * 2) ^ ((c1 & 7) << 4))) = pv1;
        }
        __syncthreads();

        // ---- dump tiles to global (coalesced) ----
        size_t blk = ((size_t)(b * 64 + g2 * 2 + t)) * 16384;
#pragma unroll
        for (int j = 0; j < 4; j++) {
            int off = tid * 16 + j * 4096;
            int4 dk = *(int4*)(smem + KO + off);
            *(int4*)(kg + blk + off) = dk;
            int4 dv = *(int4*)(smem + VB + off);
            *(int4*)(vg + blk + off) = dv;
        }
        if (t == 0) {
#pragma unroll
            for (int i = 0; i < 8; i++) xa[i] = xb[i];
            __syncthreads();   // dump reads done before next tile's proj writes
        }
    }
}

// ---------------- kernel B: streaming attention from materialized k/v ----------------
__global__ __launch_bounds__(256) void kb(
    const char* __restrict__ kg, const char* __restrict__ vg,
    const float* __restrict__ qbuf, float* __restrict__ upd_acc,
    float* __restrict__ d_acc) {
    // K0 0, K1 16384, V0 32768, V1 49152, P0 65536, P1 67584
    __shared__ __align__(16) char smem[69632];
    const int VBO = 32768, PBO = 65536;

    int tid = threadIdx.x;
    int b = blockIdx.x >> 4, gt = blockIdx.x & 15;   // 4 tiles per block
    int w = tid >> 6, lane = tid & 63, hi = lane >> 4, lo = lane & 15;

    // q A-fragments (rows 11..15 zero)
    short8 qa[4];
#pragma unroll
    for (int kc = 0; kc < 4; kc++) {
        short8 f;
#pragma unroll
        for (int j = 0; j < 8; j++)
            f[j] = (lo < 11) ? (short)f2bf(qbuf[(b * 11 + lo) * 128 + kc * 32 + hi * 8 + j])
                             : (short)0;
        qa[kc] = f;
    }

    f32x4 uacc0 = {0, 0, 0, 0}, uacc1 = {0, 0, 0, 0};
    float dacc[4] = {0, 0, 0, 0};

    size_t base = ((size_t)(b * 64 + gt * 4)) * 16384;
    int reg = w * 4096;   // per-wave-owned region within each 16KB buffer

    // prologue: stage tile0 into buf0 (own region only -> no staging barrier)
#pragma unroll
    for (int j = 0; j < 4; j++) {
        int o = reg + j * 1024;
        gll16(kg + base + o + lane * 16, smem + o);
        gll16(vg + base + o + lane * 16, smem + VBO + o);
    }

#pragma unroll
    for (int t = 0; t < 4; t++) {
        int cur = t & 1;
        if (t < 3) {
            size_t tb = base + (size_t)(t + 1) * 16384;
            int nb = (t + 1) & 1;
#pragma unroll
            for (int j = 0; j < 4; j++) {
                int o = reg + j * 1024;
                gll16(kg + tb + o + lane * 16, smem + nb * 16384 + o);
                gll16(vg + tb + o + lane * 16, smem + VBO + nb * 16384 + o);
            }
            asm volatile("s_waitcnt vmcnt(8)" ::: "memory");
        } else {
            asm volatile("s_waitcnt vmcnt(0)" ::: "memory");
        }
        __builtin_amdgcn_sched_barrier(0);

        // ---- logits + softmax over slots (wave w: keys [16w,16w+16)) ----
        {
            f32x4 lacc = {0, 0, 0, 0};
            int n = w * 16 + lo;
#pragma unroll
            for (int kc = 0; kc < 4; kc++) {
                int kbyte = cur * 16384 + n * 256 + ((kc * 64 + hi * 16) ^ ((n & 7) << 4));
                short8 kf = *(short8*)(smem + kbyte);
                lacc = __builtin_amdgcn_mfma_f32_16x16x32_bf16(qa[kc], kf, lacc, 0, 0, 0);
            }
            float mx = -1e30f;
#pragma unroll
            for (int r = 0; r < 4; r++) {
                int m = hi * 4 + r;
                float v = (m < 11) ? lacc[r] : -1e30f;
                mx = fmaxf(mx, v);
            }
            mx = fmaxf(mx, __shfl_xor(mx, 16));
            mx = fmaxf(mx, __shfl_xor(mx, 32));
            float p[4]; float s = 0.f;
#pragma unroll
            for (int r = 0; r < 4; r++) {
                int m = hi * 4 + r;
                p[r] = (m < 11) ? __expf(lacc[r] - mx) : 0.f;
                s += p[r];
            }
            s += __shfl_xor(s, 16);
            s += __shfl_xor(s, 32);
            float inv = 1.f / s;
#pragma unroll
            for (int r = 0; r < 4; r++) {
                p[r] *= inv;
                dacc[r] += p[r];
                int m = hi * 4 + r;
                *(unsigned short*)(smem + PBO + cur * 2048 + m * 128 +
                                   (((w * 16 + lo) * 2) ^ ((m & 7) << 4))) = f2bf(p[r]);
            }
        }
        // p visible to all waves; vmem prefetch stays in flight (raw barrier)
        asm volatile("s_waitcnt lgkmcnt(0)" ::: "memory");
        __builtin_amdgcn_s_barrier();

        // ---- PV: uacc += p @ v (wave w owns v-cols [32w,32w+32)) ----
#pragma unroll
        for (int kc2 = 0; kc2 < 2; kc2++) {
            int pbyte = PBO + cur * 2048 + lo * 128 + ((kc2 * 64 + hi * 16) ^ ((lo & 7) << 4));
            short8 pf = *(short8*)(smem + pbyte);
            int c0 = w * 32 + lo;
            int vb0 = VBO + cur * 16384 + c0 * 128 + ((kc2 * 64 + hi * 16) ^ ((c0 & 7) << 4));
            short8 vf0 = *(short8*)(smem + vb0);
            uacc0 = __builtin_amdgcn_mfma_f32_16x16x32_bf16(pf, vf0, uacc0, 0, 0, 0);
            int c1 = c0 + 16;
            int vb1 = VBO + cur * 16384 + c1 * 128 + ((kc2 * 64 + hi * 16) ^ ((c1 & 7) << 4));
            short8 vf1 = *(short8*)(smem + vb1);
            uacc1 = __builtin_amdgcn_mfma_f32_16x16x32_bf16(pf, vf1, uacc1, 0, 0, 0);
        }
    }

    // ---- flush partials ----
#pragma unroll
    for (int r = 0; r < 4; r++) {
        int m = hi * 4 + r;
        if (m < 11) {
            atomicAdd(&upd_acc[(b * 16 + m) * 128 + w * 32 + lo], uacc0[r]);
            atomicAdd(&upd_acc[(b * 16 + m) * 128 + w * 32 + 16 + lo], uacc1[r]);
        }
    }
#pragma unroll
    for (int mask = 1; mask < 16; mask <<= 1) {
#pragma unroll
        for (int r = 0; r < 4; r++) dacc[r] += __shfl_xor(dacc[r], mask);
    }
    if (lo == 0) {
#pragma unroll
        for (int r = 0; r < 4; r++) {
            int m = hi * 4 + r;
            if (m < 11) atomicAdd(&d_acc[b * 16 + m], dacc[r]);
        }
    }
}

// ---------------- fallback kernel S (round-1, proven) ----------------
__global__ __launch_bounds__(256) void ks(
    const float* __restrict__ inputs, const float* __restrict__ gkv,
    const float* __restrict__ bkv, const float* __restrict__ Wk,
    const float* __restrict__ Wv, const float* __restrict__ qbuf,
    float* __restrict__ upd_acc, float* __restrict__ d_acc) {
    __shared__ __align__(16) char smem[51200];
    const int XO = 0, KO = 16384, VB = 32768, PO = 49152;

    int tid = threadIdx.x;
    int b = blockIdx.x >> 4, g = blockIdx.x & 15;
    int w = tid >> 6, lane = tid & 63, hi = lane >> 4, lo = lane & 15;

    short8 bk[2][4], bv[2][4];
#pragma unroll
    for (int ct = 0; ct < 2; ct++) {
        int col = w * 32 + ct * 16 + lo;
#pragma unroll
        for (int kc = 0; kc < 4; kc++) {
            short8 fk, fv;
#pragma unroll
            for (int j = 0; j < 8; j++) {
                int rr = kc * 32 + hi * 8 + j;
                fk[j] = (short)f2bf(Wk[rr * 128 + col]);
                fv[j] = (short)f2bf(Wv[rr * 128 + col]);
            }
            bk[ct][kc] = fk; bv[ct][kc] = fv;
        }
    }
    short8 qa[4];
#pragma unroll
    for (int kc = 0; kc < 4; kc++) {
        short8 f;
#pragma unroll
        for (int j = 0; j < 8; j++)
            f[j] = (lo < 11) ? (short)f2bf(qbuf[(b * 11 + lo) * 128 + kc * 32 + hi * 8 + j])
                             : (short)0;
        qa[kc] = f;
    }
    int col4 = tid & 31;
    float4 g4  = *(const float4*)(gkv + col4 * 4);
    float4 be4 = *(const float4*)(bkv + col4 * 4);

    f32x4 uacc0 = {0, 0, 0, 0}, uacc1 = {0, 0, 0, 0};
    float dacc[4] = {0, 0, 0, 0};

    const float4* inp4 = (const float4*)(inputs + ((size_t)b * NKEYS + g * 256) * 128);
    int a_ = tid >> 5;

    for (int t = 0; t < 4; t++) {
#pragma unroll
        for (int i = 0; i < 8; i++) {
            int f = tid + 256 * i;
            float4 xv = inp4[t * 2048 + f];
            int row = a_ + 8 * i;
            float s = xv.x + xv.y + xv.z + xv.w;
            float ss = xv.x * xv.x + xv.y * xv.y + xv.z * xv.z + xv.w * xv.w;
#pragma unroll
            for (int mask = 1; mask < 32; mask <<= 1) {
                s += __shfl_xor(s, mask);
                ss += __shfl_xor(ss, mask);
            }
            float mean = s * (1.f / 128.f);
            float var = ss * (1.f / 128.f) - mean * mean;
            float rstd = rsqrtf(var + 1e-5f);
            unsigned short h0 = f2bf((xv.x - mean) * rstd * g4.x + be4.x);
            unsigned short h1 = f2bf((xv.y - mean) * rstd * g4.y + be4.y);
            unsigned short h2 = f2bf((xv.z - mean) * rstd * g4.z + be4.z);
            unsigned short h3 = f2bf((xv.w - mean) * rstd * g4.w + be4.w);
            uint2 pk;
            pk.x = (unsigned)h0 | ((unsigned)h1 << 16);
            pk.y = (unsigned)h2 | ((unsigned)h3 << 16);
            int byte = row * 256 + ((col4 * 8) ^ ((row & 7) << 4));
            *(uint2*)(smem + XO + byte) = pk;
        }
        __syncthreads();
#pragma unroll
        for (int mt = 0; mt < 4; mt++) {
            f32x4 ka0 = {0,0,0,0}, ka1 = {0,0,0,0}, va0 = {0,0,0,0}, va1 = {0,0,0,0};
            int arow = mt * 16 + lo;
#pragma unroll
            for (int kc = 0; kc < 4; kc++) {
                int abyte = arow * 256 + ((kc * 64 + hi * 16) ^ ((arow & 7) << 4));
                short8 af = *(short8*)(smem + XO + abyte);
                ka0 = __builtin_amdgcn_mfma_f32_16x16x32_bf16(af, bk[0][kc], ka0, 0, 0, 0);
                ka1 = __builtin_amdgcn_mfma_f32_16x16x32_bf16(af, bk[1][kc], ka1, 0, 0, 0);
                va0 = __builtin_amdgcn_mfma_f32_16x16x32_bf16(af, bv[0][kc], va0, 0, 0, 0);
                va1 = __builtin_amdgcn_mfma_f32_16x16x32_bf16(af, bv[1][kc], va1, 0, 0, 0);
            }
#pragma unroll
            for (int r = 0; r < 4; r++) {
                int n = mt * 16 + hi * 4 + r;
                int c0 = w * 32 + lo;
                int c1 = c0 + 16;
                *(unsigned short*)(smem + KO + n * 256 + ((c0 * 2) ^ ((n & 7) << 4))) = f2bf(ka0[r]);
                *(unsigned short*)(smem + KO + n * 256 + ((c1 * 2) ^ ((n & 7) << 4))) = f2bf(ka1[r]);
                *(unsigned short*)(smem + VB + c0 * 128 + ((n * 2) ^ ((c0 & 7) << 4))) = f2bf(va0[r]);
                *(unsigned short*)(smem + VB + c1 * 128 + ((n * 2) ^ ((c1 & 7) << 4))) = f2bf(va1[r]);
            }
        }
        __syncthreads();
        {
            f32x4 lacc = {0, 0, 0, 0};
            int n = w * 16 + lo;
#pragma unroll
            for (int kc = 0; kc < 4; kc++) {
                int kbyte = n * 256 + ((kc * 64 + hi * 16) ^ ((n & 7) << 4));
                short8 kf = *(short8*)(smem + KO + kbyte);
                lacc = __builtin_amdgcn_mfma_f32_16x16x32_bf16(qa[kc], kf, lacc, 0, 0, 0);
            }
            float mx = -1e30f;
#pragma unroll
            for (int r = 0; r < 4; r++) {
                int m = hi * 4 + r;
                float v = (m < 11) ? lacc[r] : -1e30f;
                mx = fmaxf(mx, v);
            }
            mx = fmaxf(mx, __shfl_xor(mx, 16));
            mx = fmaxf(mx, __shfl_xor(mx, 32));
            float p[4]; float s = 0.f;
#pragma unroll
            for (int r = 0; r < 4; r++) {
                int m = hi * 4 + r;
                p[r] = (m < 11) ? __expf(lacc[r] - mx) : 0.f;
                s += p[r];
            }
            s += __shfl_xor(s, 16);
            s += __shfl_xor(s, 32);
            float inv = 1.f / s;
#pragma unroll
            for (int r = 0; r < 4; r++) {
                p[r] *= inv;
                dacc[r] += p[r];
                int m = hi * 4 + r;
                *(unsigned short*)(smem + PO + m * 128 + (((w * 16 + lo) * 2) ^ ((m & 7) << 4))) =
                    f2bf(p[r]);
            }
        }
        __syncthreads();
#pragma unroll
        for (int kc2 = 0; kc2 < 2; kc2++) {
            int pbyte = lo * 128 + ((kc2 * 64 + hi * 16) ^ ((lo & 7) << 4));
            short8 pf = *(short8*)(smem + PO + pbyte);
            int c0 = w * 32 + lo;
            int vb0 = c0 * 128 + ((kc2 * 64 + hi * 16) ^ ((c0 & 7) << 4));
            short8 vf0 = *(short8*)(smem + VB + vb0);
            uacc0 = __builtin_amdgcn_mfma_f32_16x16x32_bf16(pf, vf0, uacc0, 0, 0, 0);
            int c1 = c0 + 16;
            int vb1 = c1 * 128 + ((kc2 * 64 + hi * 16) ^ ((c1 & 7) << 4));
            short8 vf1 = *(short8*)(smem + VB + vb1);
            uacc1 = __builtin_amdgcn_mfma_f32_16x16x32_bf16(pf, vf1, uacc1, 0, 0, 0);
        }
    }
#pragma unroll
    for (int r = 0; r < 4; r++) {
        int m = hi * 4 + r;
        if (m < 11) {
            atomicAdd(&upd_acc[(b * 16 + m) * 128 + w * 32 + lo], uacc0[r]);
            atomicAdd(&upd_acc[(b * 16 + m) * 128 + w * 32 + 16 + lo], uacc1[r]);
        }
    }
#pragma unroll
    for (int mask = 1; mask < 16; mask <<= 1) {
#pragma unroll
        for (int r = 0; r < 4; r++) dacc[r] += __shfl_xor(dacc[r], mask);
    }
    if (lo == 0) {
#pragma unroll
        for (int r = 0; r < 4; r++) {
            int m = hi * 4 + r;
            if (m < 11) atomicAdd(&d_acc[b * 16 + m], dacc[r]);
        }
    }
}

// ---------------- kernel U: finalize + GRU cell ----------------
__global__ void ku(const float* __restrict__ upd_acc, const float* __restrict__ d_acc,
                   const float* __restrict__ qcur,
                   const float* __restrict__ W_ir, const float* __restrict__ b_ir,
                   const float* __restrict__ W_iz, const float* __restrict__ b_iz,
                   const float* __restrict__ W_hr, const float* __restrict__ W_hz,
                   const float* __restrict__ W_in, const float* __restrict__ b_in,
                   const float* __restrict__ W_hn, const float* __restrict__ b_hn,
                   float* __restrict__ qnext) {
    int bm = blockIdx.x;
    int b = bm / 11, m = bm % 11;
    int c = threadIdx.x;
    __shared__ float us[128], qs[128];
    float den = d_acc[b * 16 + m] + 1e-8f;
    us[c] = upd_acc[(b * 16 + m) * 128 + c] / den;
    qs[c] = qcur[bm * 128 + c];
    __syncthreads();
    float air = 0, aiz = 0, ain = 0, ahr = 0, ahz = 0, ahn = 0;
#pragma unroll 4
    for (int k = 0; k < 128; k++) {
        float u = us[k], q = qs[k];
        air += u * W_ir[k * 128 + c];
        aiz += u * W_iz[k * 128 + c];
        ain += u * W_in[k * 128 + c];
        ahr += q * W_hr[k * 128 + c];
        ahz += q * W_hz[k * 128 + c];
        ahn += q * W_hn[k * 128 + c];
    }
    float r = 1.f / (1.f + expf(-(air + b_ir[c] + ahr)));
    float z = 1.f / (1.f + expf(-(aiz + b_iz[c] + ahz)));
    float n = tanhf(ain + b_in[c] + r * (ahn + b_hn[c]));
    qnext[bm * 128 + c] = (1.f - z) * n + z * qs[c];
}

// ---------------- launch ----------------
extern "C" void kernel_launch(void* const* d_in, const int* in_sizes, int n_in,
                              void* d_out, int out_size, void* d_ws, size_t ws_size,
                              hipStream_t stream) {
    const float* query   = (const float*)d_in[0];
    const float* inputs  = (const float*)d_in[1];
    const float* ln_q_g  = (const float*)d_in[2];
    const float* ln_q_b  = (const float*)d_in[3];
    const float* ln_kv_g = (const float*)d_in[4];
    const float* ln_kv_b = (const float*)d_in[5];
    const float* Wq      = (const float*)d_in[6];
    const float* Wk      = (const float*)d_in[7];
    const float* Wv      = (const float*)d_in[8];
    const float* W_ir    = (const float*)d_in[9];
    const float* b_ir    = (const float*)d_in[10];
    const float* W_iz    = (const float*)d_in[11];
    const float* b_iz    = (const float*)d_in[12];
    const float* W_hr    = (const float*)d_in[13];
    const float* W_hz    = (const float*)d_in[14];
    const float* W_in    = (const float*)d_in[15];
    const float* b_in    = (const float*)d_in[16];
    const float* W_hn    = (const float*)d_in[17];
    const float* b_hn    = (const float*)d_in[18];

    char* ws = (char*)d_ws;
    float* q_buf     = (float*)(ws);             // 64*11*128 f32
    float* query_buf = (float*)(ws + 360448);    // 64*11*128 f32
    float* upd_acc   = (float*)(ws + 720896);    // 64*16*128 f32
    float* d_acc     = (float*)(ws + 1245184);   // 64*16 f32
    char*  kg        = ws + 1249280;             // 64*64 tiles * 16KB bf16 (swizzled)
    char*  vg        = kg + 67108864;
    const size_t need = 1249280ull + 2ull * 67108864ull;

    const float* cur = query;
    if (ws_size >= need) {
        ka<<<2048, 256, 0, stream>>>(inputs, ln_kv_g, ln_kv_b, Wk, Wv, kg, vg);
        for (int it = 0; it < 2; it++) {
            kq<<<704, 128, 0, stream>>>(cur, ln_q_g, ln_q_b, Wq, q_buf);
            hipMemsetAsync(ws + 720896, 0, 524288 + 4096, stream);
            kb<<<1024, 256, 0, stream>>>(kg, vg, q_buf, upd_acc, d_acc);
            float* qn = (it == 0) ? query_buf : (float*)d_out;
            ku<<<704, 128, 0, stream>>>(upd_acc, d_acc, cur,
                                        W_ir, b_ir, W_iz, b_iz, W_hr, W_hz,
                                        W_in, b_in, W_hn, b_hn, qn);
            cur = query_buf;
        }
    } else {
        for (int it = 0; it < 2; it++) {
            kq<<<704, 128, 0, stream>>>(cur, ln_q_g, ln_q_b, Wq, q_buf);
            hipMemsetAsync(ws + 720896, 0, 524288 + 4096, stream);
            ks<<<1024, 256, 0, stream>>>(inputs, ln_kv_g, ln_kv_b, Wk, Wv, q_buf, upd_acc, d_acc);
            float* qn = (it == 0) ? query_buf : (float*)d_out;
            ku<<<704, 128, 0, stream>>>(upd_acc, d_acc, cur,
                                        W_ir, b_ir, W_iz, b_iz, W_hr, W_hz,
                                        W_in, b_in, W_hn, b_hn, qn);
            cur = query_buf;
        }
    }
}